// Round 2
// baseline (114.230 us; speedup 1.0000x reference)
//
#include <hip/hip_runtime.h>
#include <hip/hip_bf16.h>
#include <stdint.h>

// ---------------------------------------------------------------------------
// Fused MLP, bf16 MFMA (32x32x16).
//   backbone: 32->128 relu -> [128->128 relu]x7 -> Wout(16, no act)   [build2]
//   cond path: concat(h,cond)[144] ->128 (no act) ->64 relu ->3      [LDS hop]
// D = W (A-operand) * act (B-operand). C/D layout (HW-verified m74/m101):
//   col = lane&31 (batch row), m = (reg&3) + 8*(reg>>2) + 4*(lane>>5)
// Cond path avoids the in-register permlane transpose: z and z2 round-trip
// through LDS (XOR-swizzled rows, same scheme as weights) relying only on the
// verified C/D mapping + plain ds ops.
// ---------------------------------------------------------------------------

typedef __attribute__((ext_vector_type(8)))  short short8;   // 8 x bf16 frag
typedef __attribute__((ext_vector_type(16))) float f32x16;   // 32x32 acc
typedef __attribute__((ext_vector_type(4)))  float float4v;

#define NTOT 262144

// ws layout (bytes); rows padded to 128B multiples (XOR swizzle bits 4..6
// stay inside a row). Sizes multiples of 4096.
#define OFF_W0    0          // 128 rows x 128B (K=32 padded to 64 cols)
#define SZ_W0     16384
#define OFF_WH(i) (16384 + (i) * 32768)   // 7 x (128 rows x 256B)
#define SZ_WH     32768
#define OFF_WOUT  245760     // 32 rows (16 real) x 256B
#define SZ_WOUT   8192
#define OFF_WC0   253952     // 128 rows x 384B (K=144 padded to 192 cols)
#define SZ_WC0    49152
#define OFF_WC1   303104     // 64 rows x 256B
#define SZ_WC1    16384
#define OFF_WC2   319488     // 32 rows (3 real) x 128B (K=64)
#define SZ_WC2    4096
#define WS_TOTAL  323584

__device__ __forceinline__ unsigned short f2bf(float v) {
  union { __hip_bfloat16 h; unsigned short u; } c;
  c.h = __float2bfloat16(v);
  return c.u;
}

// ---------------------------------------------------------------------------
// Weight prep kernel: fp32 -> bf16, pad, pre-swizzle.
// ws[base + row*SK + o] holds W[row][((o ^ ((row&7)<<4)) >> 1) ..+8) so the
// main kernel reading at ((2*col) ^ swz) gets plain columns.
// ---------------------------------------------------------------------------
__global__ __launch_bounds__(256) void convw(
    const float* __restrict__ W0, const float* __restrict__ Wh,
    const float* __restrict__ Wout, const float* __restrict__ Wc0,
    const float* __restrict__ Wc1, const float* __restrict__ Wc2,
    unsigned char* __restrict__ ws) {
  int cid = blockIdx.x * 256 + threadIdx.x;       // one 16B chunk per thread
  if (cid >= WS_TOTAL / 16) return;
  int b = cid * 16;
  const float* src; int base, rows, K, SK;
  if (b < 16384)       { base = 0;        src = W0;   rows = 128; K = 32;  SK = 128; }
  else if (b < 245760) { int i = (b - 16384) >> 15;
                         base = 16384 + (i << 15);
                         src = Wh + i * 16384;        rows = 128; K = 128; SK = 256; }
  else if (b < 253952) { base = OFF_WOUT; src = Wout; rows = 16;  K = 128; SK = 256; }
  else if (b < 303104) { base = OFF_WC0;  src = Wc0;  rows = 128; K = 144; SK = 384; }
  else if (b < 319488) { base = OFF_WC1;  src = Wc1;  rows = 64;  K = 128; SK = 256; }
  else                 { base = OFF_WC2;  src = Wc2;  rows = 3;   K = 64;  SK = 128; }
  int rel  = b - base;
  int row  = rel / SK;
  int o    = rel - row * SK;
  int col0 = (o ^ ((row & 7) << 4)) >> 1;   // 8-aligned; chunk fully in/out
  unsigned w0 = 0, w1 = 0, w2 = 0, w3 = 0;
  if (row < rows && col0 < K) {
    const float* p = src + row * K + col0;
    w0 = (unsigned)f2bf(p[0]) | ((unsigned)f2bf(p[1]) << 16);
    w1 = (unsigned)f2bf(p[2]) | ((unsigned)f2bf(p[3]) << 16);
    w2 = (unsigned)f2bf(p[4]) | ((unsigned)f2bf(p[5]) << 16);
    w3 = (unsigned)f2bf(p[6]) | ((unsigned)f2bf(p[7]) << 16);
  }
  *(uint4*)(ws + b) = make_uint4(w0, w1, w2, w3);
}

// ---------------------------------------------------------------------------
// Helpers
// ---------------------------------------------------------------------------
__device__ __forceinline__ unsigned pk2(float a, float b) {
  union { __hip_bfloat162 h2; unsigned u; } c;
  c.h2.x = __float2bfloat16(a);
  c.h2.y = __float2bfloat16(b);
  return c.u;
}

__device__ __forceinline__ short8 frag_s8(const unsigned (&f)[4]) {
  union { unsigned u[4]; short8 s; } c;
  c.u[0] = f[0]; c.u[1] = f[1]; c.u[2] = f[2]; c.u[3] = f[3];
  return c.s;
}

// a' = {a.lo32lanes, b.lo32lanes}; b' = {a.hi32lanes, b.hi32lanes}
__device__ __forceinline__ void swap32(unsigned &a, unsigned &b) {
  asm("v_permlane32_swap_b32 %0, %1" : "+v"(a), "+v"(b));
}

// From acc of m-tile t build next-layer B-frags kk'=2t (f0), 2t+1 (f1).
__device__ __forceinline__ void build2(const f32x16 &a,
                                       unsigned (&f0)[4], unsigned (&f1)[4]) {
  unsigned a00 = pk2(a[0], a[1]),   a01 = pk2(a[2], a[3]);
  unsigned b00 = pk2(a[4], a[5]),   b01 = pk2(a[6], a[7]);
  swap32(a00, b00); swap32(a01, b01);
  f0[0] = a00; f0[1] = a01; f0[2] = b00; f0[3] = b01;
  unsigned a10 = pk2(a[8],  a[9]),  a11 = pk2(a[10], a[11]);
  unsigned b10 = pk2(a[12], a[13]), b11 = pk2(a[14], a[15]);
  swap32(a10, b10); swap32(a11, b11);
  f1[0] = a10; f1[1] = a11; f1[2] = b10; f1[3] = b11;
}

// Async stage (bytes multiple of 4096) from pre-swizzled ws into LDS.
__device__ __forceinline__ void stage(const unsigned char* __restrict__ g,
                                      unsigned char* l, int bytes,
                                      int wv, int lane) {
  #pragma unroll
  for (int base = wv * 1024; base < bytes; base += 4096) {
    __builtin_amdgcn_global_load_lds(
        (const __attribute__((address_space(1))) void*)(g + base + lane * 16),
        (__attribute__((address_space(3))) void*)(l + base), 16, 0, 0);
  }
}

#define WAITVM() asm volatile("s_waitcnt vmcnt(0)" ::: "memory")

// Backbone layer: D = W * act, NKT k-tiles, NMT m-tiles, emits frags (build2).
template <int NKT, int NMT, int SK, bool RELU>
__device__ __forceinline__ void run_layer(const unsigned char* wlds,
                                          const unsigned (&cur)[2][8][4],
                                          unsigned (&nxt)[2][8][4],
                                          int n, int g) {
  const unsigned swz = (unsigned)((n & 7) << 4);
  #pragma unroll
  for (int t = 0; t < NMT; ++t) {
    f32x16 a0, a1;
    #pragma unroll
    for (int j = 0; j < 16; ++j) { a0[j] = 0.f; a1[j] = 0.f; }
    #pragma unroll
    for (int kk = 0; kk < NKT; ++kk) {
      unsigned off = (unsigned)((32 * t + n) * SK) +
                     (((unsigned)(kk * 32 + 16 * g)) ^ swz);
      short8 wf = *(const short8*)(wlds + off);
      a0 = __builtin_amdgcn_mfma_f32_32x32x16_bf16(wf, frag_s8(cur[0][kk]), a0, 0, 0, 0);
      a1 = __builtin_amdgcn_mfma_f32_32x32x16_bf16(wf, frag_s8(cur[1][kk]), a1, 0, 0, 0);
    }
    if (RELU) {
      #pragma unroll
      for (int j = 0; j < 16; ++j) {
        a0[j] = fmaxf(a0[j], 0.f);
        a1[j] = fmaxf(a1[j], 0.f);
      }
    }
    build2(a0, nxt[0][2 * t], nxt[0][2 * t + 1]);
    build2(a1, nxt[1][2 * t], nxt[1][2 * t + 1]);
  }
}

// Write acc (16 f32, one 32-wide m-tile t) as bf16 quads into act-LDS with
// XOR-swizzled rows. rowb = row byte stride. Feature f at byte (2f)^swz.
__device__ __forceinline__ void acc_to_lds(const f32x16 &a, unsigned char* zl,
                                           int row, int rowb, int t,
                                           unsigned swz) {
  #pragma unroll
  for (int q = 0; q < 4; ++q) {
    unsigned lo = pk2(a[4 * q + 0], a[4 * q + 1]);
    unsigned hi = pk2(a[4 * q + 2], a[4 * q + 3]);
    // this lane's quad covers features 32t + 8q + 4g .. +3; byte = 2*f0
    // (the 8g term is folded in by caller via swz-compatible offset calc)
    *(uint2*)(zl + row * rowb +
              (((unsigned)(64 * t + 16 * q)) ^ swz)) = make_uint2(lo, hi);
  }
}

// ---------------------------------------------------------------------------
// Main fused kernel. 256 threads = 4 waves; 64 rows/wave (2 subtiles of 32).
// LDS: bufA 32K (even weights) + bufB 48K (odd weights / Wc0; z2 overlay)
//      + zbuf 64K (cond-path z). 147456 B total -> 1 block/CU this round.
// ---------------------------------------------------------------------------
__global__ __launch_bounds__(256, 1) void mlp_fused(
    const float* __restrict__ x, const float* __restrict__ cond,
    const unsigned char* __restrict__ ws, float* __restrict__ out) {
  __shared__ __align__(16) unsigned char bufA[32768];
  __shared__ __align__(16) unsigned char bufB[49152];
  __shared__ __align__(16) unsigned char zbuf[65536];   // 4 waves x 64 x 256B

  const int tid  = threadIdx.x;
  const int lane = tid & 63;
  const int wv   = tid >> 6;
  const int g    = lane >> 5;
  const int n    = lane & 31;
  const int rowbase = blockIdx.x * 256 + wv * 64;
  const int r0 = rowbase + n;
  const int r1 = rowbase + 32 + n;
  const unsigned swz = (unsigned)((n & 7) << 4);

  unsigned FA[2][8][4], FB[2][8][4];   // [subtile][k-tile][word]

  // -- prologue: stage W0, load x frags (K=32 -> kk 0..1) --------------------
  stage(ws + OFF_W0, bufA, SZ_W0, wv, lane);
  #pragma unroll
  for (int s = 0; s < 2; ++s) {
    int row = s ? r1 : r0;
    #pragma unroll
    for (int kk = 0; kk < 2; ++kk) {
      const float4v* p = (const float4v*)(x + row * 32 + kk * 16 + 8 * g);
      float4v u0 = p[0], u1 = p[1];
      FA[s][kk][0] = pk2(u0.x, u0.y);
      FA[s][kk][1] = pk2(u0.z, u0.w);
      FA[s][kk][2] = pk2(u1.x, u1.y);
      FA[s][kk][3] = pk2(u1.z, u1.w);
    }
  }
  WAITVM(); __syncthreads();

  // -- backbone --------------------------------------------------------------
  stage(ws + OFF_WH(0), bufB, SZ_WH, wv, lane);
  run_layer<2, 4, 128, true>(bufA, FA, FB, n, g);     // L0
  WAITVM(); __syncthreads();

  stage(ws + OFF_WH(1), bufA, SZ_WH, wv, lane);
  run_layer<8, 4, 256, true>(bufB, FB, FA, n, g);     // L1
  WAITVM(); __syncthreads();

  stage(ws + OFF_WH(2), bufB, SZ_WH, wv, lane);
  run_layer<8, 4, 256, true>(bufA, FA, FB, n, g);     // L2
  WAITVM(); __syncthreads();

  stage(ws + OFF_WH(3), bufA, SZ_WH, wv, lane);
  run_layer<8, 4, 256, true>(bufB, FB, FA, n, g);     // L3
  WAITVM(); __syncthreads();

  stage(ws + OFF_WH(4), bufB, SZ_WH, wv, lane);
  run_layer<8, 4, 256, true>(bufA, FA, FB, n, g);     // L4
  WAITVM(); __syncthreads();

  stage(ws + OFF_WH(5), bufA, SZ_WH, wv, lane);
  run_layer<8, 4, 256, true>(bufB, FB, FA, n, g);     // L5
  WAITVM(); __syncthreads();

  stage(ws + OFF_WH(6), bufB, SZ_WH, wv, lane);
  run_layer<8, 4, 256, true>(bufA, FA, FB, n, g);     // L6
  WAITVM(); __syncthreads();

  stage(ws + OFF_WOUT, bufA, SZ_WOUT, wv, lane);
  run_layer<8, 4, 256, true>(bufB, FB, FA, n, g);     // L7: h now in FA
  WAITVM(); __syncthreads();

  // -- L8: Wout (16 padded to 32, no act) -> uncond_x ------------------------
  stage(ws + OFF_WC0, bufB, SZ_WC0, wv, lane);
  {
    f32x16 a0, a1;
    #pragma unroll
    for (int j = 0; j < 16; ++j) { a0[j] = 0.f; a1[j] = 0.f; }
    #pragma unroll
    for (int kk = 0; kk < 8; ++kk) {
      unsigned off = (unsigned)(n * 256) + (((unsigned)(kk * 32 + 16 * g)) ^ swz);
      short8 wf = *(const short8*)(bufA + off);
      a0 = __builtin_amdgcn_mfma_f32_32x32x16_bf16(wf, frag_s8(FA[0][kk]), a0, 0, 0, 0);
      a1 = __builtin_amdgcn_mfma_f32_32x32x16_bf16(wf, frag_s8(FA[1][kk]), a1, 0, 0, 0);
    }
    *(float4v*)(out + r0 * 16 + 4 * g)     = (float4v){a0[0], a0[1], a0[2], a0[3]};
    *(float4v*)(out + r0 * 16 + 8 + 4 * g) = (float4v){a0[4], a0[5], a0[6], a0[7]};
    *(float4v*)(out + r1 * 16 + 4 * g)     = (float4v){a1[0], a1[1], a1[2], a1[3]};
    *(float4v*)(out + r1 * 16 + 8 + 4 * g) = (float4v){a1[4], a1[5], a1[6], a1[7]};
  }
  WAITVM(); __syncthreads();

  // -- L9: z = Wc0 * [h; cond], no act; z -> zbuf (bf16, swizzled) -----------
  stage(ws + OFF_WC1, bufA, SZ_WC1, wv, lane);
  {
    // fresh cond frags from global (slot (g,i) = cond[row][8g+i])
    unsigned CF[2][4];
    #pragma unroll
    for (int s = 0; s < 2; ++s) {
      int row = s ? r1 : r0;
      const float4v* q = (const float4v*)(cond + row * 16 + 8 * g);
      float4v c0 = q[0], c1 = q[1];
      CF[s][0] = pk2(c0.x, c0.y); CF[s][1] = pk2(c0.z, c0.w);
      CF[s][2] = pk2(c1.x, c1.y); CF[s][3] = pk2(c1.z, c1.w);
    }
    unsigned char* zw = zbuf + wv * 16384;      // [64 rows][256B]
    #pragma unroll
    for (int t = 0; t < 4; ++t) {
      f32x16 a0, a1;
      #pragma unroll
      for (int j = 0; j < 16; ++j) { a0[j] = 0.f; a1[j] = 0.f; }
      #pragma unroll
      for (int kk = 0; kk < 8; ++kk) {
        unsigned off = (unsigned)((32 * t + n) * 384) +
                       (((unsigned)(kk * 32 + 16 * g)) ^ swz);
        short8 wf = *(const short8*)(bufB + off);
        a0 = __builtin_amdgcn_mfma_f32_32x32x16_bf16(wf, frag_s8(FA[0][kk]), a0, 0, 0, 0);
        a1 = __builtin_amdgcn_mfma_f32_32x32x16_bf16(wf, frag_s8(FA[1][kk]), a1, 0, 0, 0);
      }
      {  // cond k-tile (cols 128..143)
        unsigned off = (unsigned)((32 * t + n) * 384) +
                       (((unsigned)(8 * 32 + 16 * g)) ^ swz);
        short8 wf = *(const short8*)(bufB + off);
        a0 = __builtin_amdgcn_mfma_f32_32x32x16_bf16(wf, frag_s8(CF[0]), a0, 0, 0, 0);
        a1 = __builtin_amdgcn_mfma_f32_32x32x16_bf16(wf, frag_s8(CF[1]), a1, 0, 0, 0);
      }
      // write z: lane's quad q covers features 32t+8q+4g+{0..3}
      #pragma unroll
      for (int q = 0; q < 4; ++q) {
        unsigned bo = (((unsigned)(64 * t + 16 * q + 8 * g)) ^ swz);
        *(uint2*)(zw + n * 256 + bo) =
            make_uint2(pk2(a0[4 * q], a0[4 * q + 1]), pk2(a0[4 * q + 2], a0[4 * q + 3]));
        *(uint2*)(zw + (32 + n) * 256 + bo) =
            make_uint2(pk2(a1[4 * q], a1[4 * q + 1]), pk2(a1[4 * q + 2], a1[4 * q + 3]));
      }
    }
  }
  WAITVM(); __syncthreads();

  // -- L10: z2 = relu(Wc1 * z); z2 -> bufB[8K + wv*8K) (swizzled) ------------
  stage(ws + OFF_WC2, bufB, SZ_WC2, wv, lane);
  {
    unsigned char* zw = zbuf + wv * 16384;
    unsigned char* z2 = bufB + 8192 + wv * 8192;  // [64 rows][128B]
    #pragma unroll
    for (int t = 0; t < 2; ++t) {
      f32x16 a0, a1;
      #pragma unroll
      for (int j = 0; j < 16; ++j) { a0[j] = 0.f; a1[j] = 0.f; }
      #pragma unroll
      for (int kk = 0; kk < 8; ++kk) {
        unsigned ko = (((unsigned)(kk * 32 + 16 * g)) ^ swz);
        short8 wf  = *(const short8*)(bufA + (unsigned)((32 * t + n) * 256) + ko);
        short8 zf0 = *(const short8*)(zw + n * 256 + ko);
        short8 zf1 = *(const short8*)(zw + (32 + n) * 256 + ko);
        a0 = __builtin_amdgcn_mfma_f32_32x32x16_bf16(wf, zf0, a0, 0, 0, 0);
        a1 = __builtin_amdgcn_mfma_f32_32x32x16_bf16(wf, zf1, a1, 0, 0, 0);
      }
      #pragma unroll
      for (int j = 0; j < 16; ++j) {
        a0[j] = fmaxf(a0[j], 0.f);
        a1[j] = fmaxf(a1[j], 0.f);
      }
      #pragma unroll
      for (int q = 0; q < 4; ++q) {
        unsigned bo = (((unsigned)(64 * t + 16 * q + 8 * g)) ^ swz);
        *(uint2*)(z2 + n * 128 + bo) =
            make_uint2(pk2(a0[4 * q], a0[4 * q + 1]), pk2(a0[4 * q + 2], a0[4 * q + 3]));
        *(uint2*)(z2 + (32 + n) * 128 + bo) =
            make_uint2(pk2(a1[4 * q], a1[4 * q + 1]), pk2(a1[4 * q + 2], a1[4 * q + 3]));
      }
    }
  }
  WAITVM(); __syncthreads();

  // -- L11: cond_x = Wc2 * z2 (3 rows padded to 32), K=64 --------------------
  {
    unsigned char* z2 = bufB + 8192 + wv * 8192;
    f32x16 a0, a1;
    #pragma unroll
    for (int j = 0; j < 16; ++j) { a0[j] = 0.f; a1[j] = 0.f; }
    #pragma unroll
    for (int kk = 0; kk < 4; ++kk) {
      unsigned ko = (((unsigned)(kk * 32 + 16 * g)) ^ swz);
      short8 wf  = *(const short8*)(bufB + (unsigned)(n * 128) + ko);
      short8 zf0 = *(const short8*)(z2 + n * 128 + ko);
      short8 zf1 = *(const short8*)(z2 + (32 + n) * 128 + ko);
      a0 = __builtin_amdgcn_mfma_f32_32x32x16_bf16(wf, zf0, a0, 0, 0, 0);
      a1 = __builtin_amdgcn_mfma_f32_32x32x16_bf16(wf, zf1, a1, 0, 0, 0);
    }
    float* outc = out + (size_t)NTOT * 16;
    if (g == 0) {   // m = reg for regs 0..2
      outc[r0 * 3 + 0] = a0[0];
      outc[r0 * 3 + 1] = a0[1];
      outc[r0 * 3 + 2] = a0[2];
      outc[r1 * 3 + 0] = a1[0];
      outc[r1 * 3 + 1] = a1[1];
      outc[r1 * 3 + 2] = a1[2];
    }
  }
}

// ---------------------------------------------------------------------------
extern "C" void kernel_launch(void* const* d_in, const int* in_sizes, int n_in,
                              void* d_out, int out_size, void* d_ws, size_t ws_size,
                              hipStream_t stream) {
  const float* x    = (const float*)d_in[0];
  const float* cond = (const float*)d_in[1];
  const float* W0   = (const float*)d_in[2];
  const float* Wh   = (const float*)d_in[3];
  const float* Wout = (const float*)d_in[4];
  const float* Wc0  = (const float*)d_in[5];
  const float* Wc1  = (const float*)d_in[6];
  const float* Wc2  = (const float*)d_in[7];
  unsigned char* ws = (unsigned char*)d_ws;

  convw<<<dim3((WS_TOTAL / 16 + 255) / 256), dim3(256), 0, stream>>>(
      W0, Wh, Wout, Wc0, Wc1, Wc2, ws);
  mlp_fused<<<dim3(NTOT / 256), dim3(256), 0, stream>>>(
      x, cond, ws, (float*)d_out);
}

// Round 3
// 81.983 us; speedup vs baseline: 1.3933x; 1.3933x over previous
//
#include <hip/hip_runtime.h>
#include <hip/hip_bf16.h>
#include <stdint.h>

// ---------------------------------------------------------------------------
// Fused MLP, bf16 MFMA (32x32x16), 2 blocks/CU (80KB LDS).
//   backbone: 32->128 relu -> [128->128 relu]x7 -> Wout(16, no act)  [build2]
//   cond: concat(h,cond)[144] ->128 (no act) ->64 relu ->3           [LDS hop]
// D = W (A) * act (B). C/D layout (HW-verified m74/m101):
//   col = lane&31 (batch row), m = (reg&3) + 8*(reg>>2) + 4*(lane>>5)
// Round-2 verified: backbone build2 chain + LDS-hop cond path.
// Round-3 changes: 80KB carved LDS (2 blocks/CU); Wc0 cond-cols as register
// A-frags (no LDS); z in per-wave 8KB half-buffers with L10 K-split;
// single-instruction v_cvt_pk_bf16_f32 packing; 4-chain MFMA ILP; setprio.
// ---------------------------------------------------------------------------

typedef __attribute__((ext_vector_type(8)))  short short8;   // 8 x bf16 frag
typedef __attribute__((ext_vector_type(16))) float f32x16;   // 32x32 acc
typedef __attribute__((ext_vector_type(4)))  float float4v;

#define NTOT 262144

// ws layout (bytes); rows padded to 128B multiples (XOR swizzle bits 4..6
// stay inside a row). Sizes multiples of 4096.
#define OFF_W0    0          // 128 x 128B (K=32 pad 64)
#define SZ_W0     16384
#define OFF_WH(i) (16384 + (i) * 32768)   // 7 x (128 x 256B)
#define SZ_WH     32768
#define OFF_WOUT  245760     // 32 (16 real) x 256B
#define SZ_WOUT   8192
#define OFF_WC0H  253952     // 128 x 256B  (Wc0 cols 0..127 only)
#define SZ_WC0H   32768
#define OFF_WC1   286720     // 64 x 256B
#define SZ_WC1    16384
#define OFF_WC2   303104     // 32 (3 real) x 128B (K=64)
#define SZ_WC2    4096
#define WS_TOTAL  307200

__device__ __forceinline__ unsigned short f2bf(float v) {
  union { __hip_bfloat16 h; unsigned short u; } c;
  c.h = __float2bfloat16(v);
  return c.u;
}

// ---------------------------------------------------------------------------
// Weight prep: fp32 -> bf16, pad, pre-swizzle.
// ws[base + row*SK + o] holds W[row][((o ^ ((row&7)<<4)) >> 1) ..+8) so a
// reader at ((2*col) ^ swz) gets plain columns. SS = source row stride.
// ---------------------------------------------------------------------------
__global__ __launch_bounds__(256) void convw(
    const float* __restrict__ W0, const float* __restrict__ Wh,
    const float* __restrict__ Wout, const float* __restrict__ Wc0,
    const float* __restrict__ Wc1, const float* __restrict__ Wc2,
    unsigned char* __restrict__ ws) {
  int cid = blockIdx.x * 256 + threadIdx.x;       // one 16B chunk per thread
  if (cid >= WS_TOTAL / 16) return;
  int b = cid * 16;
  const float* src; int base, rows, K, SS, SK;
  if (b < 16384)       { base = 0;        src = W0;   rows = 128; SS = 32;  K = 32;  SK = 128; }
  else if (b < 245760) { int i = (b - 16384) >> 15;
                         base = 16384 + (i << 15);
                         src = Wh + i * 16384;        rows = 128; SS = 128; K = 128; SK = 256; }
  else if (b < 253952) { base = OFF_WOUT; src = Wout; rows = 16;  SS = 128; K = 128; SK = 256; }
  else if (b < 286720) { base = OFF_WC0H; src = Wc0;  rows = 128; SS = 144; K = 128; SK = 256; }
  else if (b < 303104) { base = OFF_WC1;  src = Wc1;  rows = 64;  SS = 128; K = 128; SK = 256; }
  else                 { base = OFF_WC2;  src = Wc2;  rows = 3;   SS = 64;  K = 64;  SK = 128; }
  int rel  = b - base;
  int row  = rel / SK;
  int o    = rel - row * SK;
  int col0 = (o ^ ((row & 7) << 4)) >> 1;   // 8-aligned; chunk fully in/out
  unsigned w0 = 0, w1 = 0, w2 = 0, w3 = 0;
  if (row < rows && col0 < K) {
    const float* p = src + row * SS + col0;
    w0 = (unsigned)f2bf(p[0]) | ((unsigned)f2bf(p[1]) << 16);
    w1 = (unsigned)f2bf(p[2]) | ((unsigned)f2bf(p[3]) << 16);
    w2 = (unsigned)f2bf(p[4]) | ((unsigned)f2bf(p[5]) << 16);
    w3 = (unsigned)f2bf(p[6]) | ((unsigned)f2bf(p[7]) << 16);
  }
  *(uint4*)(ws + b) = make_uint4(w0, w1, w2, w3);
}

// ---------------------------------------------------------------------------
// Helpers
// ---------------------------------------------------------------------------
// d = {lo: bf16(a), hi: bf16(b)} in ONE instruction (T12; RNE like
// __float2bfloat16). Replaces the multi-instruction HIP lowering.
__device__ __forceinline__ unsigned pk2(float a, float b) {
  unsigned d;
  asm("v_cvt_pk_bf16_f32 %0, %1, %2" : "=v"(d) : "v"(a), "v"(b));
  return d;
}

__device__ __forceinline__ short8 frag_s8(const unsigned (&f)[4]) {
  union { unsigned u[4]; short8 s; } c;
  c.u[0] = f[0]; c.u[1] = f[1]; c.u[2] = f[2]; c.u[3] = f[3];
  return c.s;
}

// a' = {a.lo32lanes, b.lo32lanes}; b' = {a.hi32lanes, b.hi32lanes}
__device__ __forceinline__ void swap32(unsigned &a, unsigned &b) {
  asm("v_permlane32_swap_b32 %0, %1" : "+v"(a), "+v"(b));
}

// From acc (m-tile t) build next-layer B-frags kk'=2t (f0), 2t+1 (f1).
__device__ __forceinline__ void build2(const f32x16 &a,
                                       unsigned (&f0)[4], unsigned (&f1)[4]) {
  unsigned a00 = pk2(a[0], a[1]),   a01 = pk2(a[2], a[3]);
  unsigned b00 = pk2(a[4], a[5]),   b01 = pk2(a[6], a[7]);
  swap32(a00, b00); swap32(a01, b01);
  f0[0] = a00; f0[1] = a01; f0[2] = b00; f0[3] = b01;
  unsigned a10 = pk2(a[8],  a[9]),  a11 = pk2(a[10], a[11]);
  unsigned b10 = pk2(a[12], a[13]), b11 = pk2(a[14], a[15]);
  swap32(a10, b10); swap32(a11, b11);
  f1[0] = a10; f1[1] = a11; f1[2] = b10; f1[3] = b11;
}

// Async stage (bytes multiple of 4096) from pre-swizzled ws into LDS.
__device__ __forceinline__ void stage(const unsigned char* __restrict__ g,
                                      unsigned char* l, int bytes,
                                      int wv, int lane) {
  #pragma unroll
  for (int base = wv * 1024; base < bytes; base += 4096) {
    __builtin_amdgcn_global_load_lds(
        (const __attribute__((address_space(1))) void*)(g + base + lane * 16),
        (__attribute__((address_space(3))) void*)(l + base), 16, 0, 0);
  }
}

#define WAITVM() asm volatile("s_waitcnt vmcnt(0)" ::: "memory")
#define SETPRIO(x) __builtin_amdgcn_s_setprio(x)

// Backbone layer, 128 outputs (4 m-tiles as 2 pairs -> 4 indep MFMA chains).
template <int NKT, int SK, bool RELU>
__device__ __forceinline__ void layer4(const unsigned char* wlds,
                                       const unsigned (&cur)[2][8][4],
                                       unsigned (&nxt)[2][8][4],
                                       int n, int g, unsigned swz) {
  #pragma unroll
  for (int tp = 0; tp < 2; ++tp) {
    f32x16 a[2][2];   // [u = t within pair][s = subtile]
    #pragma unroll
    for (int u = 0; u < 2; ++u)
      #pragma unroll
      for (int s = 0; s < 2; ++s)
        #pragma unroll
        for (int j = 0; j < 16; ++j) a[u][s][j] = 0.f;
    SETPRIO(1);
    #pragma unroll
    for (int kk = 0; kk < NKT; ++kk) {
      unsigned ko = ((unsigned)(kk * 32 + 16 * g)) ^ swz;
      short8 wf0 = *(const short8*)(wlds + (unsigned)((64 * tp + n) * SK) + ko);
      short8 wf1 = *(const short8*)(wlds + (unsigned)((64 * tp + 32 + n) * SK) + ko);
      a[0][0] = __builtin_amdgcn_mfma_f32_32x32x16_bf16(wf0, frag_s8(cur[0][kk]), a[0][0], 0, 0, 0);
      a[0][1] = __builtin_amdgcn_mfma_f32_32x32x16_bf16(wf0, frag_s8(cur[1][kk]), a[0][1], 0, 0, 0);
      a[1][0] = __builtin_amdgcn_mfma_f32_32x32x16_bf16(wf1, frag_s8(cur[0][kk]), a[1][0], 0, 0, 0);
      a[1][1] = __builtin_amdgcn_mfma_f32_32x32x16_bf16(wf1, frag_s8(cur[1][kk]), a[1][1], 0, 0, 0);
    }
    SETPRIO(0);
    #pragma unroll
    for (int u = 0; u < 2; ++u)
      #pragma unroll
      for (int s = 0; s < 2; ++s) {
        if (RELU) {
          #pragma unroll
          for (int j = 0; j < 16; ++j) a[u][s][j] = fmaxf(a[u][s][j], 0.f);
        }
        build2(a[u][s], nxt[s][4 * tp + 2 * u], nxt[s][4 * tp + 2 * u + 1]);
      }
  }
}

// ---------------------------------------------------------------------------
// Main fused kernel. 256 threads = 4 waves; 64 rows/wave (2 subtiles of 32).
// Carved 80KB LDS -> 2 blocks/CU:
//   A = lds[0..32K)  : even weights; then per-wave z half / z2 (8K each)
//   B = lds[32K..64K): odd weights; Wc0h; then Wc2 (at B, after barrier)
//   C = lds[64K..80K): Wc1
// ---------------------------------------------------------------------------
__global__ __launch_bounds__(256, 2) void mlp_fused(
    const float* __restrict__ x, const float* __restrict__ cond,
    const float* __restrict__ wc0g, const unsigned char* __restrict__ ws,
    float* __restrict__ out) {
  __shared__ __align__(16) unsigned char lds[81920];
  unsigned char* const A = lds;
  unsigned char* const B = lds + 32768;
  unsigned char* const C = lds + 65536;

  const int tid  = threadIdx.x;
  const int lane = tid & 63;
  const int wv   = tid >> 6;
  const int g    = lane >> 5;
  const int n    = lane & 31;
  const int rowbase = blockIdx.x * 256 + wv * 64;
  const int r0 = rowbase + n;
  const int r1 = rowbase + 32 + n;
  const unsigned swz = (unsigned)((n & 7) << 4);

  unsigned FA[2][8][4], FB[2][8][4];   // [subtile][k-tile][word]

  // -- prologue: stage W0 -> A, load x frags (K=32 -> kk 0..1) ---------------
  stage(ws + OFF_W0, A, SZ_W0, wv, lane);
  #pragma unroll
  for (int s = 0; s < 2; ++s) {
    int row = s ? r1 : r0;
    #pragma unroll
    for (int kk = 0; kk < 2; ++kk) {
      const float4v* p = (const float4v*)(x + row * 32 + kk * 16 + 8 * g);
      float4v u0 = p[0], u1 = p[1];
      FA[s][kk][0] = pk2(u0.x, u0.y);
      FA[s][kk][1] = pk2(u0.z, u0.w);
      FA[s][kk][2] = pk2(u1.x, u1.y);
      FA[s][kk][3] = pk2(u1.z, u1.w);
    }
  }
  WAITVM(); __syncthreads();

  // -- backbone (ping-pong A/B) ----------------------------------------------
  stage(ws + OFF_WH(0), B, SZ_WH, wv, lane);
  layer4<2, 128, true>(A, FA, FB, n, g, swz);         // L0
  WAITVM(); __syncthreads();

  stage(ws + OFF_WH(1), A, SZ_WH, wv, lane);
  layer4<8, 256, true>(B, FB, FA, n, g, swz);         // L1
  WAITVM(); __syncthreads();

  stage(ws + OFF_WH(2), B, SZ_WH, wv, lane);
  layer4<8, 256, true>(A, FA, FB, n, g, swz);         // L2
  WAITVM(); __syncthreads();

  stage(ws + OFF_WH(3), A, SZ_WH, wv, lane);
  layer4<8, 256, true>(B, FB, FA, n, g, swz);         // L3
  WAITVM(); __syncthreads();

  stage(ws + OFF_WH(4), B, SZ_WH, wv, lane);
  layer4<8, 256, true>(A, FA, FB, n, g, swz);         // L4
  WAITVM(); __syncthreads();

  stage(ws + OFF_WH(5), A, SZ_WH, wv, lane);
  layer4<8, 256, true>(B, FB, FA, n, g, swz);         // L5
  WAITVM(); __syncthreads();

  stage(ws + OFF_WH(6), B, SZ_WH, wv, lane);
  layer4<8, 256, true>(A, FA, FB, n, g, swz);         // L6
  WAITVM(); __syncthreads();

  stage(ws + OFF_WOUT, A, SZ_WOUT, wv, lane);
  layer4<8, 256, true>(B, FB, FA, n, g, swz);         // L7: h in FA
  WAITVM(); __syncthreads();

  // -- L8: Wout (A; 16 padded to 32, no act) -> uncond_x ---------------------
  // also: stage Wc0h -> B, Wc1 -> C; load cond B-frags + Wc0 cond-col A-frags.
  stage(ws + OFF_WC0H, B, SZ_WC0H, wv, lane);
  stage(ws + OFF_WC1,  C, SZ_WC1,  wv, lane);
  unsigned CF[2][4];   // cond B-frags
  unsigned CW[4][4];   // Wc0[:,128..143] A-frags per m-tile t
  {
    f32x16 a0, a1;
    #pragma unroll
    for (int j = 0; j < 16; ++j) { a0[j] = 0.f; a1[j] = 0.f; }
    SETPRIO(1);
    #pragma unroll
    for (int kk = 0; kk < 8; ++kk) {
      unsigned ko = ((unsigned)(kk * 32 + 16 * g)) ^ swz;
      short8 wf = *(const short8*)(A + (unsigned)(n * 256) + ko);
      a0 = __builtin_amdgcn_mfma_f32_32x32x16_bf16(wf, frag_s8(FA[0][kk]), a0, 0, 0, 0);
      a1 = __builtin_amdgcn_mfma_f32_32x32x16_bf16(wf, frag_s8(FA[1][kk]), a1, 0, 0, 0);
    }
    SETPRIO(0);
    *(float4v*)(out + r0 * 16 + 4 * g)     = (float4v){a0[0], a0[1], a0[2], a0[3]};
    *(float4v*)(out + r0 * 16 + 8 + 4 * g) = (float4v){a0[4], a0[5], a0[6], a0[7]};
    *(float4v*)(out + r1 * 16 + 4 * g)     = (float4v){a1[0], a1[1], a1[2], a1[3]};
    *(float4v*)(out + r1 * 16 + 8 + 4 * g) = (float4v){a1[4], a1[5], a1[6], a1[7]};
    // cond frags (latency hides under the staging drain below)
    #pragma unroll
    for (int s = 0; s < 2; ++s) {
      const float4v* q = (const float4v*)(cond + (s ? r1 : r0) * 16 + 8 * g);
      float4v c0 = q[0], c1 = q[1];
      CF[s][0] = pk2(c0.x, c0.y); CF[s][1] = pk2(c0.z, c0.w);
      CF[s][2] = pk2(c1.x, c1.y); CF[s][3] = pk2(c1.z, c1.w);
    }
    #pragma unroll
    for (int t = 0; t < 4; ++t) {
      const float4v* pc = (const float4v*)(wc0g + (32 * t + n) * 144 + 128 + 8 * g);
      float4v q0 = pc[0], q1 = pc[1];
      CW[t][0] = pk2(q0.x, q0.y); CW[t][1] = pk2(q0.z, q0.w);
      CW[t][2] = pk2(q1.x, q1.y); CW[t][3] = pk2(q1.z, q1.w);
    }
  }
  WAITVM(); __syncthreads();

  // -- cond path: L9 (z, K=144, no act) interleaved with L10 K-passes --------
  unsigned char* const zw = A + wv * 8192;   // per-wave 64 rows x 128B
  f32x16 w2[2][2];                           // L10 acc [m-tile][subtile]
  #pragma unroll
  for (int m = 0; m < 2; ++m)
    #pragma unroll
    for (int s = 0; s < 2; ++s)
      #pragma unroll
      for (int j = 0; j < 16; ++j) w2[m][s][j] = 0.f;

  #pragma unroll
  for (int th = 0; th < 2; ++th) {           // z half: t = 2th, 2th+1
    f32x16 z[2][2];                          // [u][s]
    #pragma unroll
    for (int u = 0; u < 2; ++u)
      #pragma unroll
      for (int s = 0; s < 2; ++s)
        #pragma unroll
        for (int j = 0; j < 16; ++j) z[u][s][j] = 0.f;
    SETPRIO(1);
    #pragma unroll
    for (int kk = 0; kk < 8; ++kk) {
      unsigned ko = ((unsigned)(kk * 32 + 16 * g)) ^ swz;
      short8 wf0 = *(const short8*)(B + (unsigned)((64 * th + n) * 256) + ko);
      short8 wf1 = *(const short8*)(B + (unsigned)((64 * th + 32 + n) * 256) + ko);
      z[0][0] = __builtin_amdgcn_mfma_f32_32x32x16_bf16(wf0, frag_s8(FA[0][kk]), z[0][0], 0, 0, 0);
      z[0][1] = __builtin_amdgcn_mfma_f32_32x32x16_bf16(wf0, frag_s8(FA[1][kk]), z[0][1], 0, 0, 0);
      z[1][0] = __builtin_amdgcn_mfma_f32_32x32x16_bf16(wf1, frag_s8(FA[0][kk]), z[1][0], 0, 0, 0);
      z[1][1] = __builtin_amdgcn_mfma_f32_32x32x16_bf16(wf1, frag_s8(FA[1][kk]), z[1][1], 0, 0, 0);
    }
    // cond k-tile (cols 128..143) from register A-frags
    #pragma unroll
    for (int u = 0; u < 2; ++u) {
      z[u][0] = __builtin_amdgcn_mfma_f32_32x32x16_bf16(frag_s8(CW[2 * th + u]), frag_s8(CF[0]), z[u][0], 0, 0, 0);
      z[u][1] = __builtin_amdgcn_mfma_f32_32x32x16_bf16(frag_s8(CW[2 * th + u]), frag_s8(CF[1]), z[u][1], 0, 0, 0);
    }
    SETPRIO(0);
    // write z half: feature local f = 32u + 8q + 4g (+64*th global)
    #pragma unroll
    for (int u = 0; u < 2; ++u)
      #pragma unroll
      for (int q = 0; q < 4; ++q) {
        unsigned bo = ((unsigned)(64 * u + 16 * q + 8 * g)) ^ swz;
        *(uint2*)(zw + n * 128 + bo) =
            make_uint2(pk2(z[u][0][4 * q], z[u][0][4 * q + 1]),
                       pk2(z[u][0][4 * q + 2], z[u][0][4 * q + 3]));
        *(uint2*)(zw + (32 + n) * 128 + bo) =
            make_uint2(pk2(z[u][1][4 * q], z[u][1][4 * q + 1]),
                       pk2(z[u][1][4 * q + 2], z[u][1][4 * q + 3]));
      }

    if (th == 1) {
      // all waves done reading B (Wc0h) -> overwrite with Wc2
      __syncthreads();
      stage(ws + OFF_WC2, B, SZ_WC2, wv, lane);
    }
    // L10 pass: z2 += Wc1[:, 64th..64th+63] * z-half (same-wave LDS, no barrier)
    SETPRIO(1);
    #pragma unroll
    for (int kk = 0; kk < 4; ++kk) {
      unsigned koz = ((unsigned)(kk * 32 + 16 * g)) ^ swz;
      unsigned kow = ((unsigned)((4 * th + kk) * 32 + 16 * g)) ^ swz;
      short8 zf0 = *(const short8*)(zw + n * 128 + koz);
      short8 zf1 = *(const short8*)(zw + (32 + n) * 128 + koz);
      short8 wm0 = *(const short8*)(C + (unsigned)(n * 256) + kow);
      short8 wm1 = *(const short8*)(C + (unsigned)((32 + n) * 256) + kow);
      w2[0][0] = __builtin_amdgcn_mfma_f32_32x32x16_bf16(wm0, zf0, w2[0][0], 0, 0, 0);
      w2[0][1] = __builtin_amdgcn_mfma_f32_32x32x16_bf16(wm0, zf1, w2[0][1], 0, 0, 0);
      w2[1][0] = __builtin_amdgcn_mfma_f32_32x32x16_bf16(wm1, zf0, w2[1][0], 0, 0, 0);
      w2[1][1] = __builtin_amdgcn_mfma_f32_32x32x16_bf16(wm1, zf1, w2[1][1], 0, 0, 0);
    }
    SETPRIO(0);
  }

  // -- z2 = relu(w2) -> LDS (overwrites own z half; same-wave ordering) ------
  #pragma unroll
  for (int m = 0; m < 2; ++m)
    #pragma unroll
    for (int q = 0; q < 4; ++q) {
      unsigned bo = ((unsigned)(64 * m + 16 * q + 8 * g)) ^ swz;
      *(uint2*)(zw + n * 128 + bo) =
          make_uint2(pk2(fmaxf(w2[m][0][4 * q], 0.f),     fmaxf(w2[m][0][4 * q + 1], 0.f)),
                     pk2(fmaxf(w2[m][0][4 * q + 2], 0.f), fmaxf(w2[m][0][4 * q + 3], 0.f)));
      *(uint2*)(zw + (32 + n) * 128 + bo) =
          make_uint2(pk2(fmaxf(w2[m][1][4 * q], 0.f),     fmaxf(w2[m][1][4 * q + 1], 0.f)),
                     pk2(fmaxf(w2[m][1][4 * q + 2], 0.f), fmaxf(w2[m][1][4 * q + 3], 0.f)));
    }
  WAITVM(); __syncthreads();   // Wc2 staged (all waves) + visible

  // -- L11: cond_x = Wc2 * z2 (3 rows padded to 32), K=64 --------------------
  {
    f32x16 a0, a1;
    #pragma unroll
    for (int j = 0; j < 16; ++j) { a0[j] = 0.f; a1[j] = 0.f; }
    #pragma unroll
    for (int kk = 0; kk < 4; ++kk) {
      unsigned ko = ((unsigned)(kk * 32 + 16 * g)) ^ swz;
      short8 wf  = *(const short8*)(B + (unsigned)(n * 128) + ko);
      short8 zf0 = *(const short8*)(zw + n * 128 + ko);
      short8 zf1 = *(const short8*)(zw + (32 + n) * 128 + ko);
      a0 = __builtin_amdgcn_mfma_f32_32x32x16_bf16(wf, zf0, a0, 0, 0, 0);
      a1 = __builtin_amdgcn_mfma_f32_32x32x16_bf16(wf, zf1, a1, 0, 0, 0);
    }
    float* outc = out + (size_t)NTOT * 16;
    if (g == 0) {   // m = reg for regs 0..2
      outc[r0 * 3 + 0] = a0[0];
      outc[r0 * 3 + 1] = a0[1];
      outc[r0 * 3 + 2] = a0[2];
      outc[r1 * 3 + 0] = a1[0];
      outc[r1 * 3 + 1] = a1[1];
      outc[r1 * 3 + 2] = a1[2];
    }
  }
}

// ---------------------------------------------------------------------------
extern "C" void kernel_launch(void* const* d_in, const int* in_sizes, int n_in,
                              void* d_out, int out_size, void* d_ws, size_t ws_size,
                              hipStream_t stream) {
  const float* x    = (const float*)d_in[0];
  const float* cond = (const float*)d_in[1];
  const float* W0   = (const float*)d_in[2];
  const float* Wh   = (const float*)d_in[3];
  const float* Wout = (const float*)d_in[4];
  const float* Wc0  = (const float*)d_in[5];
  const float* Wc1  = (const float*)d_in[6];
  const float* Wc2  = (const float*)d_in[7];
  unsigned char* ws = (unsigned char*)d_ws;

  convw<<<dim3((WS_TOTAL / 16 + 255) / 256), dim3(256), 0, stream>>>(
      W0, Wh, Wout, Wc0, Wc1, Wc2, ws);
  mlp_fused<<<dim3(NTOT / 256), dim3(256), 0, stream>>>(
      x, cond, Wc0, ws, (float*)d_out);
}

// Round 4
// 81.937 us; speedup vs baseline: 1.3941x; 1.0006x over previous
//
#include <hip/hip_runtime.h>
#include <hip/hip_bf16.h>
#include <stdint.h>

// ---------------------------------------------------------------------------
// Fused MLP, bf16 MFMA (32x32x16), 2 blocks/CU (80KB LDS).
//   backbone: 32->128 relu -> [128->128 relu]x7 -> Wout(16, no act)  [build2]
//   cond: concat(h,cond)[144] ->128 (no act) ->64 relu ->3           [LDS hop]
// D = W (A) * act (B). C/D layout (HW-verified m74/m101):
//   col = lane&31 (batch row), m = (reg&3) + 8*(reg>>2) + 4*(lane>>5)
// Round-4 changes vs r3 (82us):
//  * swizzle deepened to (row&15)<<4 for all 256B-stride weight buffers:
//    r3 used (row&7)<<4 -> 4 lanes/16B-slot -> 4-way bank conflict on every
//    ds_read_b128 (SQ_LDS_BANK_CONFLICT 5.96M ~ 10us). 16 slots -> 2-way = free.
//    128B-stride buffers (W0, Wc2, z, z2) keep (row&7)<<4.
//  * acc zero-init removed: persistent zero16 as C of each chain's first MFMA
//    (saves ~256 VALU-cyc/layer/wave).
// ---------------------------------------------------------------------------

typedef __attribute__((ext_vector_type(8)))  short short8;   // 8 x bf16 frag
typedef __attribute__((ext_vector_type(16))) float f32x16;   // 32x32 acc
typedef __attribute__((ext_vector_type(4)))  float float4v;

#define NTOT 262144

// ws layout (bytes); rows padded to 128B multiples. Sizes multiples of 4096.
#define OFF_W0    0          // 128 x 128B (K=32 pad 64)        swz8
#define SZ_W0     16384
#define OFF_WH(i) (16384 + (i) * 32768)   // 7 x (128 x 256B)   swz16
#define SZ_WH     32768
#define OFF_WOUT  245760     // 32 (16 real) x 256B             swz16
#define SZ_WOUT   8192
#define OFF_WC0H  253952     // 128 x 256B (Wc0 cols 0..127)    swz16
#define SZ_WC0H   32768
#define OFF_WC1   286720     // 64 x 256B                       swz16
#define SZ_WC1    16384
#define OFF_WC2   303104     // 32 (3 real) x 128B (K=64)       swz8
#define SZ_WC2    4096
#define WS_TOTAL  307200

__device__ __forceinline__ unsigned short f2bf(float v) {
  union { __hip_bfloat16 h; unsigned short u; } c;
  c.h = __float2bfloat16(v);
  return c.u;
}

// ---------------------------------------------------------------------------
// Weight prep: fp32 -> bf16, pad, pre-swizzle.
// ws[base + row*SK + o] holds W[row][((o ^ ((row&M)<<4)) >> 1) ..+8) with
// M = 15 for 256B rows, 7 for 128B rows, so a reader at ((2*col) ^ swz)
// gets plain columns. SS = source row stride.
// ---------------------------------------------------------------------------
__global__ __launch_bounds__(256) void convw(
    const float* __restrict__ W0, const float* __restrict__ Wh,
    const float* __restrict__ Wout, const float* __restrict__ Wc0,
    const float* __restrict__ Wc1, const float* __restrict__ Wc2,
    unsigned char* __restrict__ ws) {
  int cid = blockIdx.x * 256 + threadIdx.x;       // one 16B chunk per thread
  if (cid >= WS_TOTAL / 16) return;
  int b = cid * 16;
  const float* src; int base, rows, K, SS, SK;
  if (b < 16384)       { base = 0;        src = W0;   rows = 128; SS = 32;  K = 32;  SK = 128; }
  else if (b < 245760) { int i = (b - 16384) >> 15;
                         base = 16384 + (i << 15);
                         src = Wh + i * 16384;        rows = 128; SS = 128; K = 128; SK = 256; }
  else if (b < 253952) { base = OFF_WOUT; src = Wout; rows = 16;  SS = 128; K = 128; SK = 256; }
  else if (b < 286720) { base = OFF_WC0H; src = Wc0;  rows = 128; SS = 144; K = 128; SK = 256; }
  else if (b < 303104) { base = OFF_WC1;  src = Wc1;  rows = 64;  SS = 128; K = 128; SK = 256; }
  else                 { base = OFF_WC2;  src = Wc2;  rows = 3;   SS = 64;  K = 64;  SK = 128; }
  int rel  = b - base;
  int row  = rel / SK;
  int o    = rel - row * SK;
  int M    = (SK >= 256) ? 15 : 7;
  int col0 = (o ^ ((row & M) << 4)) >> 1;   // 8-aligned; chunk fully in/out
  unsigned w0 = 0, w1 = 0, w2 = 0, w3 = 0;
  if (row < rows && col0 < K) {
    const float* p = src + row * SS + col0;
    w0 = (unsigned)f2bf(p[0]) | ((unsigned)f2bf(p[1]) << 16);
    w1 = (unsigned)f2bf(p[2]) | ((unsigned)f2bf(p[3]) << 16);
    w2 = (unsigned)f2bf(p[4]) | ((unsigned)f2bf(p[5]) << 16);
    w3 = (unsigned)f2bf(p[6]) | ((unsigned)f2bf(p[7]) << 16);
  }
  *(uint4*)(ws + b) = make_uint4(w0, w1, w2, w3);
}

// ---------------------------------------------------------------------------
// Helpers
// ---------------------------------------------------------------------------
// d = {lo: bf16(a), hi: bf16(b)} in ONE instruction (T12 recipe, RNE).
__device__ __forceinline__ unsigned pk2(float a, float b) {
  unsigned d;
  asm("v_cvt_pk_bf16_f32 %0, %1, %2" : "=v"(d) : "v"(a), "v"(b));
  return d;
}

__device__ __forceinline__ short8 frag_s8(const unsigned (&f)[4]) {
  union { unsigned u[4]; short8 s; } c;
  c.u[0] = f[0]; c.u[1] = f[1]; c.u[2] = f[2]; c.u[3] = f[3];
  return c.s;
}

// a' = {a.lo32lanes, b.lo32lanes}; b' = {a.hi32lanes, b.hi32lanes}
__device__ __forceinline__ void swap32(unsigned &a, unsigned &b) {
  asm("v_permlane32_swap_b32 %0, %1" : "+v"(a), "+v"(b));
}

// From acc (m-tile t) build next-layer B-frags kk'=2t (f0), 2t+1 (f1).
__device__ __forceinline__ void build2(const f32x16 &a,
                                       unsigned (&f0)[4], unsigned (&f1)[4]) {
  unsigned a00 = pk2(a[0], a[1]),   a01 = pk2(a[2], a[3]);
  unsigned b00 = pk2(a[4], a[5]),   b01 = pk2(a[6], a[7]);
  swap32(a00, b00); swap32(a01, b01);
  f0[0] = a00; f0[1] = a01; f0[2] = b00; f0[3] = b01;
  unsigned a10 = pk2(a[8],  a[9]),  a11 = pk2(a[10], a[11]);
  unsigned b10 = pk2(a[12], a[13]), b11 = pk2(a[14], a[15]);
  swap32(a10, b10); swap32(a11, b11);
  f1[0] = a10; f1[1] = a11; f1[2] = b10; f1[3] = b11;
}

// Async stage (bytes multiple of 4096) from pre-swizzled ws into LDS.
__device__ __forceinline__ void stage(const unsigned char* __restrict__ g,
                                      unsigned char* l, int bytes,
                                      int wv, int lane) {
  #pragma unroll
  for (int base = wv * 1024; base < bytes; base += 4096) {
    __builtin_amdgcn_global_load_lds(
        (const __attribute__((address_space(1))) void*)(g + base + lane * 16),
        (__attribute__((address_space(3))) void*)(l + base), 16, 0, 0);
  }
}

#define WAITVM() asm volatile("s_waitcnt vmcnt(0)" ::: "memory")
#define SETPRIO(x) __builtin_amdgcn_s_setprio(x)
#define MFMA(A_, B_, C_) __builtin_amdgcn_mfma_f32_32x32x16_bf16(A_, B_, C_, 0, 0, 0)

// Backbone layer, 128 outputs (4 m-tiles as 2 pairs -> 4 indep MFMA chains).
// First k-tile uses zero16 as C (no per-layer acc zero-init).
template <int NKT, int SK, bool RELU>
__device__ __forceinline__ void layer4(const unsigned char* wlds,
                                       const unsigned (&cur)[2][8][4],
                                       unsigned (&nxt)[2][8][4],
                                       int n, int g, unsigned swz,
                                       const f32x16 &zero16) {
  #pragma unroll
  for (int tp = 0; tp < 2; ++tp) {
    f32x16 a[2][2];   // [u = t within pair][s = subtile]
    SETPRIO(1);
    #pragma unroll
    for (int kk = 0; kk < NKT; ++kk) {
      unsigned ko = ((unsigned)(kk * 32 + 16 * g)) ^ swz;
      short8 wf0 = *(const short8*)(wlds + (unsigned)((64 * tp + n) * SK) + ko);
      short8 wf1 = *(const short8*)(wlds + (unsigned)((64 * tp + 32 + n) * SK) + ko);
      if (kk == 0) {
        a[0][0] = MFMA(wf0, frag_s8(cur[0][0]), zero16);
        a[0][1] = MFMA(wf0, frag_s8(cur[1][0]), zero16);
        a[1][0] = MFMA(wf1, frag_s8(cur[0][0]), zero16);
        a[1][1] = MFMA(wf1, frag_s8(cur[1][0]), zero16);
      } else {
        a[0][0] = MFMA(wf0, frag_s8(cur[0][kk]), a[0][0]);
        a[0][1] = MFMA(wf0, frag_s8(cur[1][kk]), a[0][1]);
        a[1][0] = MFMA(wf1, frag_s8(cur[0][kk]), a[1][0]);
        a[1][1] = MFMA(wf1, frag_s8(cur[1][kk]), a[1][1]);
      }
    }
    SETPRIO(0);
    #pragma unroll
    for (int u = 0; u < 2; ++u)
      #pragma unroll
      for (int s = 0; s < 2; ++s) {
        if (RELU) {
          #pragma unroll
          for (int j = 0; j < 16; ++j) a[u][s][j] = fmaxf(a[u][s][j], 0.f);
        }
        build2(a[u][s], nxt[s][4 * tp + 2 * u], nxt[s][4 * tp + 2 * u + 1]);
      }
  }
}

// ---------------------------------------------------------------------------
// Main fused kernel. 256 threads = 4 waves; 64 rows/wave (2 subtiles of 32).
// Carved 80KB LDS -> 2 blocks/CU:
//   A = lds[0..32K)  : even weights; then per-wave z half / z2 (8K each)
//   B = lds[32K..64K): odd weights; Wc0h; then Wc2 (after barrier)
//   C = lds[64K..80K): Wc1
// ---------------------------------------------------------------------------
__global__ __launch_bounds__(256, 2) void mlp_fused(
    const float* __restrict__ x, const float* __restrict__ cond,
    const float* __restrict__ wc0g, const unsigned char* __restrict__ ws,
    float* __restrict__ out) {
  __shared__ __align__(16) unsigned char lds[81920];
  unsigned char* const A = lds;
  unsigned char* const B = lds + 32768;
  unsigned char* const C = lds + 65536;

  const int tid  = threadIdx.x;
  const int lane = tid & 63;
  const int wv   = tid >> 6;
  const int g    = lane >> 5;
  const int n    = lane & 31;
  const int rowbase = blockIdx.x * 256 + wv * 64;
  const int r0 = rowbase + n;
  const int r1 = rowbase + 32 + n;
  const unsigned swz8  = (unsigned)((n & 7) << 4);    // 128B-stride buffers
  const unsigned swz16 = (unsigned)((n & 15) << 4);   // 256B-stride buffers

  f32x16 zero16;
  #pragma unroll
  for (int j = 0; j < 16; ++j) zero16[j] = 0.f;

  unsigned FA[2][8][4], FB[2][8][4];   // [subtile][k-tile][word]

  // -- prologue: stage W0 -> A, load x frags (K=32 -> kk 0..1) ---------------
  stage(ws + OFF_W0, A, SZ_W0, wv, lane);
  #pragma unroll
  for (int s = 0; s < 2; ++s) {
    int row = s ? r1 : r0;
    #pragma unroll
    for (int kk = 0; kk < 2; ++kk) {
      const float4v* p = (const float4v*)(x + row * 32 + kk * 16 + 8 * g);
      float4v u0 = p[0], u1 = p[1];
      FA[s][kk][0] = pk2(u0.x, u0.y);
      FA[s][kk][1] = pk2(u0.z, u0.w);
      FA[s][kk][2] = pk2(u1.x, u1.y);
      FA[s][kk][3] = pk2(u1.z, u1.w);
    }
  }
  WAITVM(); __syncthreads();

  // -- backbone (ping-pong A/B) ----------------------------------------------
  stage(ws + OFF_WH(0), B, SZ_WH, wv, lane);
  layer4<2, 128, true>(A, FA, FB, n, g, swz8, zero16);    // L0 (W0: 128B rows)
  WAITVM(); __syncthreads();

  stage(ws + OFF_WH(1), A, SZ_WH, wv, lane);
  layer4<8, 256, true>(B, FB, FA, n, g, swz16, zero16);   // L1
  WAITVM(); __syncthreads();

  stage(ws + OFF_WH(2), B, SZ_WH, wv, lane);
  layer4<8, 256, true>(A, FA, FB, n, g, swz16, zero16);   // L2
  WAITVM(); __syncthreads();

  stage(ws + OFF_WH(3), A, SZ_WH, wv, lane);
  layer4<8, 256, true>(B, FB, FA, n, g, swz16, zero16);   // L3
  WAITVM(); __syncthreads();

  stage(ws + OFF_WH(4), B, SZ_WH, wv, lane);
  layer4<8, 256, true>(A, FA, FB, n, g, swz16, zero16);   // L4
  WAITVM(); __syncthreads();

  stage(ws + OFF_WH(5), A, SZ_WH, wv, lane);
  layer4<8, 256, true>(B, FB, FA, n, g, swz16, zero16);   // L5
  WAITVM(); __syncthreads();

  stage(ws + OFF_WH(6), B, SZ_WH, wv, lane);
  layer4<8, 256, true>(A, FA, FB, n, g, swz16, zero16);   // L6
  WAITVM(); __syncthreads();

  stage(ws + OFF_WOUT, A, SZ_WOUT, wv, lane);
  layer4<8, 256, true>(B, FB, FA, n, g, swz16, zero16);   // L7: h in FA
  WAITVM(); __syncthreads();

  // -- L8: Wout (A; 16 padded to 32, no act) -> uncond_x ---------------------
  // also: stage Wc0h -> B, Wc1 -> C; load cond B-frags + Wc0 cond-col A-frags.
  stage(ws + OFF_WC0H, B, SZ_WC0H, wv, lane);
  stage(ws + OFF_WC1,  C, SZ_WC1,  wv, lane);
  unsigned CF[2][4];   // cond B-frags
  unsigned CW[4][4];   // Wc0[:,128..143] A-frags per m-tile t
  {
    f32x16 a0, a1;
    SETPRIO(1);
    #pragma unroll
    for (int kk = 0; kk < 8; ++kk) {
      unsigned ko = ((unsigned)(kk * 32 + 16 * g)) ^ swz16;
      short8 wf = *(const short8*)(A + (unsigned)(n * 256) + ko);
      if (kk == 0) {
        a0 = MFMA(wf, frag_s8(FA[0][0]), zero16);
        a1 = MFMA(wf, frag_s8(FA[1][0]), zero16);
      } else {
        a0 = MFMA(wf, frag_s8(FA[0][kk]), a0);
        a1 = MFMA(wf, frag_s8(FA[1][kk]), a1);
      }
    }
    SETPRIO(0);
    *(float4v*)(out + r0 * 16 + 4 * g)     = (float4v){a0[0], a0[1], a0[2], a0[3]};
    *(float4v*)(out + r0 * 16 + 8 + 4 * g) = (float4v){a0[4], a0[5], a0[6], a0[7]};
    *(float4v*)(out + r1 * 16 + 4 * g)     = (float4v){a1[0], a1[1], a1[2], a1[3]};
    *(float4v*)(out + r1 * 16 + 8 + 4 * g) = (float4v){a1[4], a1[5], a1[6], a1[7]};
    // cond frags (latency hides under the staging drain below)
    #pragma unroll
    for (int s = 0; s < 2; ++s) {
      const float4v* q = (const float4v*)(cond + (s ? r1 : r0) * 16 + 8 * g);
      float4v c0 = q[0], c1 = q[1];
      CF[s][0] = pk2(c0.x, c0.y); CF[s][1] = pk2(c0.z, c0.w);
      CF[s][2] = pk2(c1.x, c1.y); CF[s][3] = pk2(c1.z, c1.w);
    }
    #pragma unroll
    for (int t = 0; t < 4; ++t) {
      const float4v* pc = (const float4v*)(wc0g + (32 * t + n) * 144 + 128 + 8 * g);
      float4v q0 = pc[0], q1 = pc[1];
      CW[t][0] = pk2(q0.x, q0.y); CW[t][1] = pk2(q0.z, q0.w);
      CW[t][2] = pk2(q1.x, q1.y); CW[t][3] = pk2(q1.z, q1.w);
    }
  }
  WAITVM(); __syncthreads();

  // -- cond path: L9 (z, K=144, no act) interleaved with L10 K-passes --------
  unsigned char* const zw = A + wv * 8192;   // per-wave 64 rows x 128B (swz8)
  f32x16 w2[2][2];                           // L10 acc [m-tile][subtile]

  #pragma unroll
  for (int th = 0; th < 2; ++th) {           // z half: t = 2th, 2th+1
    f32x16 z[2][2];                          // [u][s]
    SETPRIO(1);
    #pragma unroll
    for (int kk = 0; kk < 8; ++kk) {
      unsigned ko = ((unsigned)(kk * 32 + 16 * g)) ^ swz16;
      short8 wf0 = *(const short8*)(B + (unsigned)((64 * th + n) * 256) + ko);
      short8 wf1 = *(const short8*)(B + (unsigned)((64 * th + 32 + n) * 256) + ko);
      if (kk == 0) {
        z[0][0] = MFMA(wf0, frag_s8(FA[0][0]), zero16);
        z[0][1] = MFMA(wf0, frag_s8(FA[1][0]), zero16);
        z[1][0] = MFMA(wf1, frag_s8(FA[0][0]), zero16);
        z[1][1] = MFMA(wf1, frag_s8(FA[1][0]), zero16);
      } else {
        z[0][0] = MFMA(wf0, frag_s8(FA[0][kk]), z[0][0]);
        z[0][1] = MFMA(wf0, frag_s8(FA[1][kk]), z[0][1]);
        z[1][0] = MFMA(wf1, frag_s8(FA[0][kk]), z[1][0]);
        z[1][1] = MFMA(wf1, frag_s8(FA[1][kk]), z[1][1]);
      }
    }
    // cond k-tile (cols 128..143) from register A-frags
    #pragma unroll
    for (int u = 0; u < 2; ++u) {
      z[u][0] = MFMA(frag_s8(CW[2 * th + u]), frag_s8(CF[0]), z[u][0]);
      z[u][1] = MFMA(frag_s8(CW[2 * th + u]), frag_s8(CF[1]), z[u][1]);
    }
    SETPRIO(0);
    // write z half: feature local f = 32u + 8q + 4g (+64*th global)
    #pragma unroll
    for (int u = 0; u < 2; ++u)
      #pragma unroll
      for (int q = 0; q < 4; ++q) {
        unsigned bo = ((unsigned)(64 * u + 16 * q + 8 * g)) ^ swz8;
        *(uint2*)(zw + n * 128 + bo) =
            make_uint2(pk2(z[u][0][4 * q], z[u][0][4 * q + 1]),
                       pk2(z[u][0][4 * q + 2], z[u][0][4 * q + 3]));
        *(uint2*)(zw + (32 + n) * 128 + bo) =
            make_uint2(pk2(z[u][1][4 * q], z[u][1][4 * q + 1]),
                       pk2(z[u][1][4 * q + 2], z[u][1][4 * q + 3]));
      }

    if (th == 1) {
      // all waves done reading B (Wc0h) -> overwrite with Wc2
      __syncthreads();
      stage(ws + OFF_WC2, B, SZ_WC2, wv, lane);
    }
    // L10 pass: z2 += Wc1[:, 64th..64th+63] * z-half (same-wave LDS, no barrier)
    SETPRIO(1);
    #pragma unroll
    for (int kk = 0; kk < 4; ++kk) {
      unsigned koz = ((unsigned)(kk * 32 + 16 * g)) ^ swz8;
      unsigned kow = ((unsigned)((4 * th + kk) * 32 + 16 * g)) ^ swz16;
      short8 zf0 = *(const short8*)(zw + n * 128 + koz);
      short8 zf1 = *(const short8*)(zw + (32 + n) * 128 + koz);
      short8 wm0 = *(const short8*)(C + (unsigned)(n * 256) + kow);
      short8 wm1 = *(const short8*)(C + (unsigned)((32 + n) * 256) + kow);
      if (th == 0 && kk == 0) {
        w2[0][0] = MFMA(wm0, zf0, zero16);
        w2[0][1] = MFMA(wm0, zf1, zero16);
        w2[1][0] = MFMA(wm1, zf0, zero16);
        w2[1][1] = MFMA(wm1, zf1, zero16);
      } else {
        w2[0][0] = MFMA(wm0, zf0, w2[0][0]);
        w2[0][1] = MFMA(wm0, zf1, w2[0][1]);
        w2[1][0] = MFMA(wm1, zf0, w2[1][0]);
        w2[1][1] = MFMA(wm1, zf1, w2[1][1]);
      }
    }
    SETPRIO(0);
  }

  // -- z2 = relu(w2) -> LDS (overwrites own z half; same-wave ordering) ------
  #pragma unroll
  for (int m = 0; m < 2; ++m)
    #pragma unroll
    for (int q = 0; q < 4; ++q) {
      unsigned bo = ((unsigned)(64 * m + 16 * q + 8 * g)) ^ swz8;
      *(uint2*)(zw + n * 128 + bo) =
          make_uint2(pk2(fmaxf(w2[m][0][4 * q], 0.f),     fmaxf(w2[m][0][4 * q + 1], 0.f)),
                     pk2(fmaxf(w2[m][0][4 * q + 2], 0.f), fmaxf(w2[m][0][4 * q + 3], 0.f)));
      *(uint2*)(zw + (32 + n) * 128 + bo) =
          make_uint2(pk2(fmaxf(w2[m][1][4 * q], 0.f),     fmaxf(w2[m][1][4 * q + 1], 0.f)),
                     pk2(fmaxf(w2[m][1][4 * q + 2], 0.f), fmaxf(w2[m][1][4 * q + 3], 0.f)));
    }
  WAITVM(); __syncthreads();   // Wc2 staged (all waves) + visible

  // -- L11: cond_x = Wc2 * z2 (3 rows padded to 32), K=64 --------------------
  {
    f32x16 a0, a1;
    #pragma unroll
    for (int kk = 0; kk < 4; ++kk) {
      unsigned ko = ((unsigned)(kk * 32 + 16 * g)) ^ swz8;
      short8 wf  = *(const short8*)(B + (unsigned)(n * 128) + ko);
      short8 zf0 = *(const short8*)(zw + n * 128 + ko);
      short8 zf1 = *(const short8*)(zw + (32 + n) * 128 + ko);
      if (kk == 0) {
        a0 = MFMA(wf, zf0, zero16);
        a1 = MFMA(wf, zf1, zero16);
      } else {
        a0 = MFMA(wf, zf0, a0);
        a1 = MFMA(wf, zf1, a1);
      }
    }
    float* outc = out + (size_t)NTOT * 16;
    if (g == 0) {   // m = reg for regs 0..2
      outc[r0 * 3 + 0] = a0[0];
      outc[r0 * 3 + 1] = a0[1];
      outc[r0 * 3 + 2] = a0[2];
      outc[r1 * 3 + 0] = a1[0];
      outc[r1 * 3 + 1] = a1[1];
      outc[r1 * 3 + 2] = a1[2];
    }
  }
}

// ---------------------------------------------------------------------------
extern "C" void kernel_launch(void* const* d_in, const int* in_sizes, int n_in,
                              void* d_out, int out_size, void* d_ws, size_t ws_size,
                              hipStream_t stream) {
  const float* x    = (const float*)d_in[0];
  const float* cond = (const float*)d_in[1];
  const float* W0   = (const float*)d_in[2];
  const float* Wh   = (const float*)d_in[3];
  const float* Wout = (const float*)d_in[4];
  const float* Wc0  = (const float*)d_in[5];
  const float* Wc1  = (const float*)d_in[6];
  const float* Wc2  = (const float*)d_in[7];
  unsigned char* ws = (unsigned char*)d_ws;

  convw<<<dim3((WS_TOTAL / 16 + 255) / 256), dim3(256), 0, stream>>>(
      W0, Wh, Wout, Wc0, Wc1, Wc2, ws);
  mlp_fused<<<dim3(NTOT / 256), dim3(256), 0, stream>>>(
      x, cond, Wc0, ws, (float*)d_out);
}

// Round 5
// 79.434 us; speedup vs baseline: 1.4380x; 1.0315x over previous
//
#include <hip/hip_runtime.h>
#include <hip/hip_bf16.h>
#include <stdint.h>

// ---------------------------------------------------------------------------
// Fused MLP, bf16 MFMA (32x32x16). Round-5 structure:
//  * chunk-packed weights: per (m-tile t, k-tile kk) a 1KB chunk; lane l
//    holds W[32t+(l&31)][16kk+8*(l>>5) .. +7]. Reads are lane-linear
//    ds_read_b128 (stride-1, conflict-free, no swizzle).
//  * 21 half-layer phases over 3 rotating 16KB LDS buffers; stage issued 2
//    phases ahead; raw s_barrier + counted vmcnt(N) (T3+T4) -- no full
//    vmcnt(0) drains in the steady-state loop.
//  * cond path continues the FA/FB register ping-pong (ZF=FB, Z2=FA);
//    no activation LDS at all. C/D layout (HW-verified m74/m101):
//    col = lane&31 (batch row), m = (reg&3)+8*(reg>>2)+4*(lane>>5).
// ---------------------------------------------------------------------------

typedef __attribute__((ext_vector_type(8)))  short short8;   // 8 x bf16 frag
typedef __attribute__((ext_vector_type(16))) float f32x16;   // 32x32 acc
typedef __attribute__((ext_vector_type(4)))  float float4v;

#define NTOT 262144

// chunk-packed ws layout (bytes). Region = M/32 x K/16 x 1KB.
#define CW0    0          // W0:   4t x 2kk  = 8KB
#define CWH(i) (8192 + (i) * 32768)   // Wh[i]: 4t x 8kk = 32KB, i=0..6
#define CWOUT  237568     // Wout: 1t x 8kk = 8KB (rows 16..31 zero)
#define CWC0   245760     // Wc0 cols 0..127: 4t x 8kk = 32KB
#define CWC1   278528     // Wc1:  2t x 8kk = 16KB
#define CWC2   294912     // Wc2:  1t x 4kk = 4KB (rows 3..31 zero)
#define WS_TOTAL 299008

__device__ __forceinline__ unsigned short f2bf(float v) {
  union { __hip_bfloat16 h; unsigned short u; } c;
  c.h = __float2bfloat16(v);
  return c.u;
}

// ---------------------------------------------------------------------------
// Weight prep: fp32 -> bf16 chunk packing. One 16B piece per thread.
// chunk c = t*NKT + kk at region base + c*1024; byte l*16 belongs to lane l:
// W[32t + (l&31)][16kk + 8*(l>>5) .. +7].
// ---------------------------------------------------------------------------
__global__ __launch_bounds__(256) void convw(
    const float* __restrict__ W0, const float* __restrict__ Wh,
    const float* __restrict__ Wout, const float* __restrict__ Wc0,
    const float* __restrict__ Wc1, const float* __restrict__ Wc2,
    unsigned char* __restrict__ ws) {
  int cid = blockIdx.x * 256 + threadIdx.x;
  if (cid >= WS_TOTAL / 16) return;
  int b = cid * 16;
  const float* src; int base, rows, SS, NKT;
  if (b < 8192)        { base = CW0;   src = W0;   rows = 128; SS = 32;  NKT = 2; }
  else if (b < 237568) { int i = (b - 8192) >> 15;
                         base = 8192 + (i << 15);
                         src = Wh + i * 16384;      rows = 128; SS = 128; NKT = 8; }
  else if (b < 245760) { base = CWOUT; src = Wout; rows = 16;  SS = 128; NKT = 8; }
  else if (b < 278528) { base = CWC0;  src = Wc0;  rows = 128; SS = 144; NKT = 8; }
  else if (b < 294912) { base = CWC1;  src = Wc1;  rows = 64;  SS = 128; NKT = 8; }
  else                 { base = CWC2;  src = Wc2;  rows = 3;   SS = 64;  NKT = 4; }
  int rel = b - base;
  int c   = rel >> 10;
  int t   = c / NKT, kk = c - t * NKT;
  int l   = (rel & 1023) >> 4;
  int n   = l & 31, g = l >> 5;
  int row = 32 * t + n, col = 16 * kk + 8 * g;
  unsigned w0 = 0, w1 = 0, w2 = 0, w3 = 0;
  if (row < rows) {
    const float* p = src + row * SS + col;
    w0 = (unsigned)f2bf(p[0]) | ((unsigned)f2bf(p[1]) << 16);
    w1 = (unsigned)f2bf(p[2]) | ((unsigned)f2bf(p[3]) << 16);
    w2 = (unsigned)f2bf(p[4]) | ((unsigned)f2bf(p[5]) << 16);
    w3 = (unsigned)f2bf(p[6]) | ((unsigned)f2bf(p[7]) << 16);
  }
  *(uint4*)(ws + b) = make_uint4(w0, w1, w2, w3);
}

// ---------------------------------------------------------------------------
// Helpers
// ---------------------------------------------------------------------------
__device__ __forceinline__ unsigned pk2(float a, float b) {
  unsigned d;
  asm("v_cvt_pk_bf16_f32 %0, %1, %2" : "=v"(d) : "v"(a), "v"(b));
  return d;
}

__device__ __forceinline__ short8 frag_s8(const unsigned (&f)[4]) {
  union { unsigned u[4]; short8 s; } c;
  c.u[0] = f[0]; c.u[1] = f[1]; c.u[2] = f[2]; c.u[3] = f[3];
  return c.s;
}

__device__ __forceinline__ void swap32(unsigned &a, unsigned &b) {
  asm("v_permlane32_swap_b32 %0, %1" : "+v"(a), "+v"(b));
}

// From acc (m-tile t) build next-layer B-frags kk'=2t (f0), 2t+1 (f1).
__device__ __forceinline__ void build2(const f32x16 &a,
                                       unsigned (&f0)[4], unsigned (&f1)[4]) {
  unsigned a00 = pk2(a[0], a[1]),   a01 = pk2(a[2], a[3]);
  unsigned b00 = pk2(a[4], a[5]),   b01 = pk2(a[6], a[7]);
  swap32(a00, b00); swap32(a01, b01);
  f0[0] = a00; f0[1] = a01; f0[2] = b00; f0[3] = b01;
  unsigned a10 = pk2(a[8],  a[9]),  a11 = pk2(a[10], a[11]);
  unsigned b10 = pk2(a[12], a[13]), b11 = pk2(a[14], a[15]);
  swap32(a10, b10); swap32(a11, b11);
  f1[0] = a10; f1[1] = a11; f1[2] = b10; f1[3] = b11;
}

// Async stage `bytes` (4096/8192/16384) from chunk-packed ws into LDS.
__device__ __forceinline__ void stage(const unsigned char* __restrict__ g,
                                      unsigned char* l, int bytes,
                                      int wv, int lane) {
  #pragma unroll
  for (int base = wv * 1024; base < bytes; base += 4096) {
    __builtin_amdgcn_global_load_lds(
        (const __attribute__((address_space(1))) void*)(g + base + lane * 16),
        (__attribute__((address_space(3))) void*)(l + base), 16, 0, 0);
  }
}

#define VMCNT_(N) asm volatile("s_waitcnt vmcnt(" #N ")" ::: "memory")
#define VMCNT(N) VMCNT_(N)
#define BAR() __builtin_amdgcn_s_barrier()
#define SETPRIO(x) __builtin_amdgcn_s_setprio(x)
#define MFMA(A_, B_, C_) __builtin_amdgcn_mfma_f32_32x32x16_bf16(A_, B_, C_, 0, 0, 0)

// Half-layer: 2 m-tiles (u=0,1), NKT k-tiles, 4 indep MFMA chains.
// lb = lds + bufoff + lane*16. Writes nxt frags hb..hb+3.
template <int NKT, bool RELU>
__device__ __forceinline__ void half_phase(const unsigned char* lb,
                                           const unsigned (&cur)[2][8][4],
                                           unsigned (&nxt)[2][8][4], int hb,
                                           const f32x16 &zero16) {
  f32x16 a[2][2];
  SETPRIO(1);
  #pragma unroll
  for (int kk = 0; kk < NKT; ++kk) {
    short8 wf0 = *(const short8*)(lb + kk * 1024);
    short8 wf1 = *(const short8*)(lb + NKT * 1024 + kk * 1024);
    if (kk == 0) {
      a[0][0] = MFMA(wf0, frag_s8(cur[0][0]), zero16);
      a[0][1] = MFMA(wf0, frag_s8(cur[1][0]), zero16);
      a[1][0] = MFMA(wf1, frag_s8(cur[0][0]), zero16);
      a[1][1] = MFMA(wf1, frag_s8(cur[1][0]), zero16);
    } else {
      a[0][0] = MFMA(wf0, frag_s8(cur[0][kk]), a[0][0]);
      a[0][1] = MFMA(wf0, frag_s8(cur[1][kk]), a[0][1]);
      a[1][0] = MFMA(wf1, frag_s8(cur[0][kk]), a[1][0]);
      a[1][1] = MFMA(wf1, frag_s8(cur[1][kk]), a[1][1]);
    }
  }
  SETPRIO(0);
  #pragma unroll
  for (int u = 0; u < 2; ++u)
    #pragma unroll
    for (int s = 0; s < 2; ++s) {
      if (RELU) {
        #pragma unroll
        for (int j = 0; j < 16; ++j) a[u][s][j] = fmaxf(a[u][s][j], 0.f);
      }
      build2(a[u][s], nxt[s][hb + 2 * u], nxt[s][hb + 2 * u + 1]);
    }
}

// L9 half: Wc0 cols 0..127 from LDS + cond k-tile (cols 128..143) from regs.
__device__ __forceinline__ void half_c9(const unsigned char* lb,
                                        const unsigned (&cur)[2][8][4],
                                        unsigned (&nxt)[2][8][4], int hb,
                                        const unsigned (&cw0)[4],
                                        const unsigned (&cw1)[4],
                                        const unsigned (&cf)[2][4],
                                        const f32x16 &zero16) {
  f32x16 a[2][2];
  SETPRIO(1);
  #pragma unroll
  for (int kk = 0; kk < 8; ++kk) {
    short8 wf0 = *(const short8*)(lb + kk * 1024);
    short8 wf1 = *(const short8*)(lb + 8192 + kk * 1024);
    if (kk == 0) {
      a[0][0] = MFMA(wf0, frag_s8(cur[0][0]), zero16);
      a[0][1] = MFMA(wf0, frag_s8(cur[1][0]), zero16);
      a[1][0] = MFMA(wf1, frag_s8(cur[0][0]), zero16);
      a[1][1] = MFMA(wf1, frag_s8(cur[1][0]), zero16);
    } else {
      a[0][0] = MFMA(wf0, frag_s8(cur[0][kk]), a[0][0]);
      a[0][1] = MFMA(wf0, frag_s8(cur[1][kk]), a[0][1]);
      a[1][0] = MFMA(wf1, frag_s8(cur[0][kk]), a[1][0]);
      a[1][1] = MFMA(wf1, frag_s8(cur[1][kk]), a[1][1]);
    }
  }
  a[0][0] = MFMA(frag_s8(cw0), frag_s8(cf[0]), a[0][0]);
  a[0][1] = MFMA(frag_s8(cw0), frag_s8(cf[1]), a[0][1]);
  a[1][0] = MFMA(frag_s8(cw1), frag_s8(cf[0]), a[1][0]);
  a[1][1] = MFMA(frag_s8(cw1), frag_s8(cf[1]), a[1][1]);
  SETPRIO(0);
  #pragma unroll
  for (int u = 0; u < 2; ++u)
    #pragma unroll
    for (int s = 0; s < 2; ++s)
      build2(a[u][s], nxt[s][hb + 2 * u], nxt[s][hb + 2 * u + 1]);  // no relu
}

// ---------------------------------------------------------------------------
// Main fused kernel. 256 threads = 4 waves; 64 rows/wave.
// LDS: 3 x 16KB rotating half-layer buffers (48KB). Raw barriers + counted
// vmcnt; staging always 2 phases ahead.
// ---------------------------------------------------------------------------
__global__ __launch_bounds__(256, 2) void mlp_fused(
    const float* __restrict__ x, const float* __restrict__ cond,
    const float* __restrict__ wc0g, const unsigned char* __restrict__ ws,
    float* __restrict__ out) {
  __shared__ __align__(16) unsigned char lds[49152];

  const int tid  = threadIdx.x;
  const int lane = tid & 63;
  const int wv   = tid >> 6;
  const int g    = lane >> 5;
  const int n    = lane & 31;
  const int rowbase = blockIdx.x * 256 + wv * 64;
  const int r0 = rowbase + n;
  const int r1 = rowbase + 32 + n;
  const unsigned char* ldsL = lds + lane * 16;

  f32x16 zero16;
  #pragma unroll
  for (int j = 0; j < 16; ++j) zero16[j] = 0.f;

  unsigned FA[2][8][4], FB[2][8][4];   // [subtile][k-tile][word]

  // -- prologue: x frags; stage P0 (W0 h0 -> b0), P1 (W0 h1 -> b1) -----------
  #pragma unroll
  for (int s = 0; s < 2; ++s) {
    int row = s ? r1 : r0;
    #pragma unroll
    for (int kk = 0; kk < 2; ++kk) {
      const float4v* p = (const float4v*)(x + row * 32 + kk * 16 + 8 * g);
      float4v u0 = p[0], u1 = p[1];
      FA[s][kk][0] = pk2(u0.x, u0.y);
      FA[s][kk][1] = pk2(u0.z, u0.w);
      FA[s][kk][2] = pk2(u1.x, u1.y);
      FA[s][kk][3] = pk2(u1.z, u1.w);
    }
  }
  stage(ws + CW0,        lds,         4096, wv, lane);
  stage(ws + CW0 + 4096, lds + 16384, 4096, wv, lane);
  VMCNT(1); BAR();

  // -- backbone: L0 (2 phases) + L1..L7 (14 phases) --------------------------
  // P0/P1: L0 halves (NKT=2), FA -> FB
  stage(ws + CWH(0),         lds + 32768, 16384, wv, lane);
  half_phase<2, true>(ldsL,          FA, FB, 0, zero16);
  VMCNT(4); BAR();
  stage(ws + CWH(0) + 16384, lds,         16384, wv, lane);
  half_phase<2, true>(ldsL + 16384,  FA, FB, 4, zero16);
  VMCNT(4); BAR();

  // P2..P13: L1..L6 (NKT=8), ping-pong; buffers cycle 2,0,1,2,0,1,...
  stage(ws + CWH(1),         lds + 16384, 16384, wv, lane);   // P2 (b2)
  half_phase<8, true>(ldsL + 32768,  FB, FA, 0, zero16);
  VMCNT(4); BAR();
  stage(ws + CWH(1) + 16384, lds + 32768, 16384, wv, lane);   // P3 (b0)
  half_phase<8, true>(ldsL,          FB, FA, 4, zero16);
  VMCNT(4); BAR();

  stage(ws + CWH(2),         lds,         16384, wv, lane);   // P4 (b1)
  half_phase<8, true>(ldsL + 16384,  FA, FB, 0, zero16);
  VMCNT(4); BAR();
  stage(ws + CWH(2) + 16384, lds + 16384, 16384, wv, lane);   // P5 (b2)
  half_phase<8, true>(ldsL + 32768,  FA, FB, 4, zero16);
  VMCNT(4); BAR();

  stage(ws + CWH(3),         lds + 32768, 16384, wv, lane);   // P6 (b0)
  half_phase<8, true>(ldsL,          FB, FA, 0, zero16);
  VMCNT(4); BAR();
  stage(ws + CWH(3) + 16384, lds,         16384, wv, lane);   // P7 (b1)
  half_phase<8, true>(ldsL + 16384,  FB, FA, 4, zero16);
  VMCNT(4); BAR();

  stage(ws + CWH(4),         lds + 16384, 16384, wv, lane);   // P8 (b2)
  half_phase<8, true>(ldsL + 32768,  FA, FB, 0, zero16);
  VMCNT(4); BAR();
  stage(ws + CWH(4) + 16384, lds + 32768, 16384, wv, lane);   // P9 (b0)
  half_phase<8, true>(ldsL,          FA, FB, 4, zero16);
  VMCNT(4); BAR();

  stage(ws + CWH(5),         lds,         16384, wv, lane);   // P10 (b1)
  half_phase<8, true>(ldsL + 16384,  FB, FA, 0, zero16);
  VMCNT(4); BAR();
  stage(ws + CWH(5) + 16384, lds + 16384, 16384, wv, lane);   // P11 (b2)
  half_phase<8, true>(ldsL + 32768,  FB, FA, 4, zero16);
  VMCNT(4); BAR();

  stage(ws + CWH(6),         lds + 32768, 16384, wv, lane);   // P12 (b0)
  half_phase<8, true>(ldsL,          FA, FB, 0, zero16);
  VMCNT(4); BAR();
  stage(ws + CWH(6) + 16384, lds,         16384, wv, lane);   // P13 (b1)
  half_phase<8, true>(ldsL + 16384,  FA, FB, 4, zero16);
  VMCNT(4); BAR();

  // P14: L7 h0 (b2); stage Wout (8KB) -> b1
  stage(ws + CWOUT, lds + 16384, 8192, wv, lane);
  half_phase<8, true>(ldsL + 32768,  FB, FA, 0, zero16);
  VMCNT(2); BAR();
  // P15: L7 h1 (b0); stage Wc0 h0 -> b2.  h now in FA.
  stage(ws + CWC0, lds + 32768, 16384, wv, lane);
  half_phase<8, true>(ldsL,          FB, FA, 4, zero16);
  VMCNT(4); BAR();

  // -- P16: Wout (b1, 1 m-tile, no act) -> uncond_x; CF loads; stage Wc0 h1 --
  unsigned CF[2][4];
  {
    stage(ws + CWC0 + 16384, lds, 16384, wv, lane);   // -> b0 for P18
    #pragma unroll
    for (int s = 0; s < 2; ++s) {
      const float4v* q = (const float4v*)(cond + (s ? r1 : r0) * 16 + 8 * g);
      float4v c0 = q[0], c1 = q[1];
      CF[s][0] = pk2(c0.x, c0.y); CF[s][1] = pk2(c0.z, c0.w);
      CF[s][2] = pk2(c1.x, c1.y); CF[s][3] = pk2(c1.z, c1.w);
    }
    const unsigned char* lb = ldsL + 16384;
    f32x16 a0, a1;
    SETPRIO(1);
    #pragma unroll
    for (int kk = 0; kk < 8; ++kk) {
      short8 wf = *(const short8*)(lb + kk * 1024);
      if (kk == 0) {
        a0 = MFMA(wf, frag_s8(FA[0][0]), zero16);
        a1 = MFMA(wf, frag_s8(FA[1][0]), zero16);
      } else {
        a0 = MFMA(wf, frag_s8(FA[0][kk]), a0);
        a1 = MFMA(wf, frag_s8(FA[1][kk]), a1);
      }
    }
    SETPRIO(0);
    *(float4v*)(out + r0 * 16 + 4 * g)     = (float4v){a0[0], a0[1], a0[2], a0[3]};
    *(float4v*)(out + r0 * 16 + 8 + 4 * g) = (float4v){a0[4], a0[5], a0[6], a0[7]};
    *(float4v*)(out + r1 * 16 + 4 * g)     = (float4v){a1[0], a1[1], a1[2], a1[3]};
    *(float4v*)(out + r1 * 16 + 8 + 4 * g) = (float4v){a1[4], a1[5], a1[6], a1[7]};
  }
  VMCNT(12); BAR();

  // -- P17: L9 h0 (b2): Wc0 rows 0..63 + cond k-tile; stage Wc1 -> b1 --------
  {
    unsigned CW0r[4], CW1r[4];
    #pragma unroll
    for (int u = 0; u < 2; ++u) {
      const float4v* pc = (const float4v*)(wc0g + (32 * u + n) * 144 + 128 + 8 * g);
      float4v q0 = pc[0], q1 = pc[1];
      unsigned* cw = u ? CW1r : CW0r;
      cw[0] = pk2(q0.x, q0.y); cw[1] = pk2(q0.z, q0.w);
      cw[2] = pk2(q1.x, q1.y); cw[3] = pk2(q1.z, q1.w);
    }
    stage(ws + CWC1, lds, 16384, wv, lane);   // -> b1 for P19
    half_c9(ldsL + 32768, FA, FB, 0, CW0r, CW1r, CF, zero16);
  }
  VMCNT(16); BAR();

  // -- P18: L9 h1 (b0): Wc0 rows 64..127 + cond k-tile; stage Wc2 -> b2 ------
  {
    unsigned CW0r[4], CW1r[4];
    #pragma unroll
    for (int u = 0; u < 2; ++u) {
      const float4v* pc = (const float4v*)(wc0g + (32 * (2 + u) + n) * 144 + 128 + 8 * g);
      float4v q0 = pc[0], q1 = pc[1];
      unsigned* cw = u ? CW1r : CW0r;
      cw[0] = pk2(q0.x, q0.y); cw[1] = pk2(q0.z, q0.w);
      cw[2] = pk2(q1.x, q1.y); cw[3] = pk2(q1.z, q1.w);
    }
    stage(ws + CWC2, lds + 16384, 4096, wv, lane);   // -> b2 for P20
    half_c9(ldsL, FA, FB, 4, CW0r, CW1r, CF, zero16);
  }
  VMCNT(5); BAR();

  // -- P19: L10 / Wc1 (b1): z2 = relu(Wc1 * z), z in FB -> Z2 frags in FA ----
  half_phase<8, true>(ldsL, FB, FA, 0, zero16);
  VMCNT(0); BAR();

  // -- P20: L11 / Wc2 (b2): cond_x = Wc2 * z2 (3 rows), K=64 -----------------
  {
    const unsigned char* lb = ldsL + 16384;
    f32x16 a0, a1;
    #pragma unroll
    for (int kk = 0; kk < 4; ++kk) {
      short8 wf = *(const short8*)(lb + kk * 1024);
      if (kk == 0) {
        a0 = MFMA(wf, frag_s8(FA[0][0]), zero16);
        a1 = MFMA(wf, frag_s8(FA[1][0]), zero16);
      } else {
        a0 = MFMA(wf, frag_s8(FA[0][kk]), a0);
        a1 = MFMA(wf, frag_s8(FA[1][kk]), a1);
      }
    }
    float* outc = out + (size_t)NTOT * 16;
    if (g == 0) {   // m = reg for regs 0..2
      outc[r0 * 3 + 0] = a0[0];
      outc[r0 * 3 + 1] = a0[1];
      outc[r0 * 3 + 2] = a0[2];
      outc[r1 * 3 + 0] = a1[0];
      outc[r1 * 3 + 1] = a1[1];
      outc[r1 * 3 + 2] = a1[2];
    }
  }
}

// ---------------------------------------------------------------------------
extern "C" void kernel_launch(void* const* d_in, const int* in_sizes, int n_in,
                              void* d_out, int out_size, void* d_ws, size_t ws_size,
                              hipStream_t stream) {
  const float* x    = (const float*)d_in[0];
  const float* cond = (const float*)d_in[1];
  const float* W0   = (const float*)d_in[2];
  const float* Wh   = (const float*)d_in[3];
  const float* Wout = (const float*)d_in[4];
  const float* Wc0  = (const float*)d_in[5];
  const float* Wc1  = (const float*)d_in[6];
  const float* Wc2  = (const float*)d_in[7];
  unsigned char* ws = (unsigned char*)d_ws;

  convw<<<dim3((WS_TOTAL / 16 + 255) / 256), dim3(256), 0, stream>>>(
      W0, Wh, Wout, Wc0, Wc1, Wc2, ws);
  mlp_fused<<<dim3(NTOT / 256), dim3(256), 0, stream>>>(
      x, cond, Wc0, ws, (float*)d_out);
}